// Round 9
// baseline (225.292 us; speedup 1.0000x reference)
//
#include <hip/hip_runtime.h>

// Self-attention (B=8, N=4096, C=128) + residual + inference BatchNorm.
// R9: R8's proven DMA-dbuf flash core, restructured for 4 blocks/CU:
//   - 64-key tiles: LDS = 2x16K (K dbuf) + 8K (P) = 40 KB -> 4 blocks/CU.
//   - split-K x2 (additive partials via no-max exp2 softmax), grid 1024.
//   - S-phase waves split q (qf = 16 VGPRs, was 64); PV splits d.
//     Persistent regs ~64 -> 4 waves/SIMD without any launch-bounds forcing.
//   - P bf16 pack by truncation (3 VALU vs 12; P in [0,1], 4.5x err headroom).
//   - combine kernel (verified in R5) merges the 2 key-halves + residual + BN.
//
// ws: Wt 96KB | Qg 8M | Kg(swizzled) 8M | Vtg 8M | Ow 32M | lw 256K (~58 MB;
// R5 ran this split layout on this harness, so ws_size suffices).

typedef __attribute__((ext_vector_type(8))) short bf16x8;
typedef __attribute__((ext_vector_type(4))) float f32x4;

__device__ __forceinline__ unsigned short f2bf(float f) {
  unsigned int u = __builtin_bit_cast(unsigned int, f);
  u += 0x7fffu + ((u >> 16) & 1u);   // RNE
  return (unsigned short)(u >> 16);
}
__device__ __forceinline__ unsigned int pack2(float a, float b) {
  return (unsigned int)f2bf(a) | ((unsigned int)f2bf(b) << 16);
}
// truncating pack (P in [0,1]: bias negligible, saves ~9 VALU per pair)
__device__ __forceinline__ unsigned int pack2t(float a, float b) {
  return (__builtin_bit_cast(unsigned int, a) >> 16) |
         (__builtin_bit_cast(unsigned int, b) & 0xFFFF0000u);
}

// async global->LDS DMA, 16B/lane: lds dest = uniform base + lane*16
__device__ __forceinline__ void dma16(const void* g, void* l) {
  __builtin_amdgcn_global_load_lds(
      (const __attribute__((address_space(1))) unsigned int*)g,
      (__attribute__((address_space(3))) unsigned int*)l, 16, 0, 0);
}

// 1/sqrt(128) * log2(e): softmax in exp2 domain; folded into Wq/bq.
#define SCALE_Q (0.08838834764831845f * 1.44269504088896340f)

// ---------------------------------------------------------------------------
// Kernel 1: W[k][n] fp32 -> Wt[n][k] bf16 (Wq pre-scaled)
// ---------------------------------------------------------------------------
__global__ void prep_wt(const float* __restrict__ wq, const float* __restrict__ wk,
                        const float* __restrict__ wv, unsigned short* __restrict__ wt) {
  const float* W = (blockIdx.x == 0) ? wq : (blockIdx.x == 1 ? wk : wv);
  const float sc = (blockIdx.x == 0) ? SCALE_Q : 1.0f;
  unsigned short* out = wt + blockIdx.x * 16384;
  int id = blockIdx.y * 256 + threadIdx.x;
  int n  = id >> 5;
  int kb = (id & 31) * 4;
#pragma unroll
  for (int k = 0; k < 4; ++k)
    out[n * 128 + kb + k] = f2bf(W[(kb + k) * 128 + n] * sc);
}

// ---------------------------------------------------------------------------
// Kernel 2: QKV projection, grid(512, 3). K stored pre-swizzled (chunk ^ row)
// so flash's linear DMA lands conflict-free in LDS.
// ---------------------------------------------------------------------------
__global__ __launch_bounds__(256) void qkv_proj(
    const float* __restrict__ x, const unsigned short* __restrict__ wt,
    const float* __restrict__ bq, const float* __restrict__ bk, const float* __restrict__ bv,
    unsigned short* __restrict__ Qg, unsigned short* __restrict__ Kg,
    unsigned short* __restrict__ Vtg) {
  __shared__ unsigned short xs[64 * 128];    // swizzled bf16 x tile (16 KB)
  __shared__ unsigned short obuf[9216];      // bounce buffer (18 KB)
  const int t = threadIdx.x;
  const int p = blockIdx.y;
  const int rowblk = blockIdx.x * 64;

#pragma unroll
  for (int i = 0; i < 8; ++i) {
    int flat = t * 4 + i * 1024;
    int row = flat >> 7, col = flat & 127;
    float4 v = *(const float4*)(x + (size_t)(rowblk + row) * 128 + col);
    unsigned int u0 = pack2(v.x, v.y), u1 = pack2(v.z, v.w);
    int pos = (col >> 3) ^ (row & 15);
    *(uint2*)(xs + row * 128 + pos * 8 + (col & 7)) = make_uint2(u0, u1);
  }
  __syncthreads();

  const int lane = t & 63, wv_ = t >> 6;
  const int lm = lane & 15, quad = lane >> 4;

  bf16x8 a[4];
  {
    int row = wv_ * 16 + lm;
#pragma unroll
    for (int ks = 0; ks < 4; ++ks)
      a[ks] = __builtin_bit_cast(bf16x8,
          *(const uint4*)(xs + row * 128 + (((ks * 4 + quad) ^ lm) * 8)));
  }

  const unsigned short* w = wt + p * 16384;
  const float* bias = (p == 0) ? bq : (p == 1 ? bk : bv);
  const float bsc = (p == 0) ? SCALE_Q : 1.0f;

  const f32x4 zero4 = {0.f, 0.f, 0.f, 0.f};
  f32x4 acc[8];
#pragma unroll
  for (int ct = 0; ct < 8; ++ct) acc[ct] = zero4;

#pragma unroll
  for (int ct = 0; ct < 8; ++ct) {
    int n = ct * 16 + lm;
    const uint4* wp = (const uint4*)(w + n * 128 + quad * 8);
#pragma unroll
    for (int ks = 0; ks < 4; ++ks) {
      bf16x8 bfr = __builtin_bit_cast(bf16x8, wp[ks * 4]);
      acc[ct] = __builtin_amdgcn_mfma_f32_16x16x32_bf16(a[ks], bfr, acc[ct], 0, 0, 0);
    }
  }

  const int b   = rowblk >> 12;
  const int nb0 = rowblk & 4095;

  if (p < 2) {
    int rowb = wv_ * 16 + quad * 4;
#pragma unroll
    for (int ct = 0; ct < 8; ++ct) {
      int c = ct * 16 + lm;
      float bb = bias[c] * bsc;
#pragma unroll
      for (int r = 0; r < 4; ++r)
        obuf[(rowb + r) * 136 + c] = f2bf(acc[ct][r] + bb);
    }
    __syncthreads();
    unsigned short* og = (p == 0) ? Qg : Kg;
    int row = t >> 2;
#pragma unroll
    for (int j = 0; j < 4; ++j) {
      int ch = (t & 3) * 4 + j;
      int pos = (p == 1) ? (ch ^ (row & 15)) : ch;   // K: pre-swizzle for DMA
      uint4 vv = *(const uint4*)(obuf + row * 136 + ch * 8);
      *(uint4*)(og + (size_t)(rowblk + row) * 128 + pos * 8) = vv;
    }
  } else {
    int key_base = wv_ * 16 + quad * 4;
#pragma unroll
    for (int ct = 0; ct < 8; ++ct) {
      int c = ct * 16 + lm;
      float bb = bias[c];
      unsigned int u0 = pack2(acc[ct][0] + bb, acc[ct][1] + bb);
      unsigned int u1 = pack2(acc[ct][2] + bb, acc[ct][3] + bb);
      *(uint2*)(obuf + c * 72 + key_base) = make_uint2(u0, u1);
    }
    __syncthreads();
    int d = t >> 1;
#pragma unroll
    for (int j = 0; j < 4; ++j) {
      int ch = (t & 1) * 4 + j;
      uint4 vv = *(const uint4*)(obuf + d * 72 + ch * 8);
      *(uint4*)(Vtg + (size_t)b * 524288 + (size_t)d * 4096 + nb0 + ch * 8) = vv;
    }
  }
}

// ---------------------------------------------------------------------------
// Kernel 3: flash attention, split-K x2, 64-key tiles, DMA-dbuf K.
// grid(1024): b = bx&7, kh = (bx>>3)&1, qt = bx>>4. 256 thr = 4 waves.
// S-phase: wave w computes S^T (all 64 keys x its 16 q). PV: wave w owns
// d[w*32..+32) x all 64 q. Writes additive partials Ow[slot], lw[slot].
// LDS 40 KB -> 4 blocks/CU.
// ---------------------------------------------------------------------------
__global__ __launch_bounds__(256) void flash_attn(
    const unsigned short* __restrict__ Qg, const unsigned short* __restrict__ Kg,
    const unsigned short* __restrict__ Vtg,
    float* __restrict__ Ow, float* __restrict__ lw) {
  __shared__ unsigned short Kt[2][8192];   // 2 x 16 KB (64 keys x 128 d), swizzled
  __shared__ unsigned short Pbuf[4096];    // 8 KB: 64 q x 64 keys, swizzled

  const int b  = blockIdx.x & 7;
  const int kh = (blockIdx.x >> 3) & 1;
  const int qt = blockIdx.x >> 4;          // 0..63
  const int slot = (b * 64 + qt) * 2 + kh;
  const int t = threadIdx.x;
  const int lane = t & 63;
  const int w = t >> 6;                    // 0..3
  const int lm = lane & 15, quad = lane >> 4;
  const int q0 = qt * 64;
  const int keybase = kh * 2048;

  const unsigned short* Qb = Qg  + (size_t)b * 524288;
  const unsigned short* Kb = Kg  + (size_t)b * 524288;
  const unsigned short* Vb = Vtg + (size_t)b * 524288;

  // Q B-frags: this wave's 16 q rows (16 VGPRs persistent)
  bf16x8 qf[4];
  {
    const uint4* qp = (const uint4*)(Qb + (size_t)(q0 + w * 16 + lm) * 128 + quad * 8);
#pragma unroll
    for (int ks = 0; ks < 4; ++ks) qf[ks] = __builtin_bit_cast(bf16x8, qp[ks * 4]);
  }

  const f32x4 zero4 = {0.f, 0.f, 0.f, 0.f};
  f32x4 o[2][4];                           // O^T: wave's 32 d x 64 q
#pragma unroll
  for (int mt = 0; mt < 2; ++mt)
#pragma unroll
    for (int nt = 0; nt < 4; ++nt) o[mt][nt] = zero4;
  float lp = 0.f;                          // l for q = w*16+lm (this wave's q)

  // preload K tile 0 (wave DMAs its 4 KB quarter = 16 key-rows)
  {
    const unsigned short* src = Kb + (size_t)keybase * 128 + w * 2048 + lane * 8;
    unsigned short* dst = &Kt[0][w * 2048];
#pragma unroll
    for (int j = 0; j < 4; ++j) dma16(src + j * 512, dst + j * 512);
  }
  __syncthreads();

#pragma unroll 1
  for (int kt = 0; kt < 32; ++kt) {
    const int bi = kt & 1;
    const int key0 = keybase + kt * 64;

    // V^T A-frags (wave's 32 d x this tile's 64 keys); fly through S-phase
    bf16x8 vf[2][2];
#pragma unroll
    for (int mt = 0; mt < 2; ++mt)
#pragma unroll
      for (int ks = 0; ks < 2; ++ks)
        vf[mt][ks] = __builtin_bit_cast(bf16x8,
            *(const uint4*)(Vb + (size_t)(w * 32 + mt * 16 + lm) * 4096 +
                            key0 + ks * 32 + quad * 8));

    // S^T = K * Q^T: all 64 keys (mt 0..3) x wave's 16 q
    f32x4 sa[4];
#pragma unroll
    for (int mt = 0; mt < 4; ++mt) sa[mt] = zero4;
#pragma unroll
    for (int mt = 0; mt < 4; ++mt) {
      const unsigned short* kr = &Kt[bi][(mt * 16 + lm) * 128];
      bf16x8 kf[4];
#pragma unroll
      for (int ks = 0; ks < 4; ++ks)
        kf[ks] = __builtin_bit_cast(bf16x8, *(const uint4*)(kr + ((ks * 4 + quad) ^ lm) * 8));
#pragma unroll
      for (int ks = 0; ks < 4; ++ks)
        sa[mt] = __builtin_amdgcn_mfma_f32_16x16x32_bf16(kf[ks], qf[ks], sa[mt], 0, 0, 0);
    }

    // no-max softmax: P = exp2(S~); row q = w*16+lm, key = mt*16+quad*4+r
    {
      const int prow = w * 16 + lm;
      const int sub = (quad & 1) * 4;
#pragma unroll
      for (int mt = 0; mt < 4; ++mt) {
        float e0 = exp2f(sa[mt][0]), e1 = exp2f(sa[mt][1]);
        float e2 = exp2f(sa[mt][2]), e3 = exp2f(sa[mt][3]);
        lp += (e0 + e1) + (e2 + e3);
        int pos = (mt * 2 + (quad >> 1)) ^ (lm & 7);
        *(uint2*)(Pbuf + prow * 64 + pos * 8 + sub) =
            make_uint2(pack2t(e0, e1), pack2t(e2, e3));
      }
    }
    __syncthreads();   // barrier 1: P complete, K[t] free, vf drained

    // async DMA K[t+1] (drains at barrier 2, covered by PV)
    if (kt + 1 < 32) {
      const unsigned short* src = Kb + (size_t)(key0 + 64) * 128 + w * 2048 + lane * 8;
      unsigned short* dst = &Kt[bi ^ 1][w * 2048];
#pragma unroll
      for (int j = 0; j < 4; ++j) dma16(src + j * 512, dst + j * 512);
    }

    // O^T += V^T * P^T (wave's 32 d x all 64 q, K=64 keys)
    {
      const uint4* Pr = (const uint4*)Pbuf;
#pragma unroll
      for (int nt = 0; nt < 4; ++nt) {
        bf16x8 pf[2];
#pragma unroll
        for (int ks = 0; ks < 2; ++ks)
          pf[ks] = __builtin_bit_cast(bf16x8,
              Pr[(nt * 16 + lm) * 8 + (((ks * 4 + quad) ^ (lm & 7)))]);
#pragma unroll
        for (int ks = 0; ks < 2; ++ks)
#pragma unroll
          for (int mt = 0; mt < 2; ++mt)
            o[mt][nt] = __builtin_amdgcn_mfma_f32_16x16x32_bf16(vf[mt][ks], pf[ks], o[mt][nt], 0, 0, 0);
      }
    }
    __syncthreads();   // barrier 2: P free; K[t+1] resident
  }

  // l: reduce over quads (keys); wave owns q = w*16+lm exclusively
  lp += __shfl_xor(lp, 16);
  lp += __shfl_xor(lp, 32);
  if (quad == 0) lw[(size_t)slot * 64 + w * 16 + lm] = lp;

  // partial O store: Ow[slot][q][d], float4 (4 consecutive d per reg-quad)
  float* Op = Ow + (size_t)slot * 8192;
#pragma unroll
  for (int mt = 0; mt < 2; ++mt) {
    int d0 = w * 32 + mt * 16 + quad * 4;
#pragma unroll
    for (int nt = 0; nt < 4; ++nt) {
      float4 ov;
      ov.x = o[mt][nt][0]; ov.y = o[mt][nt][1];
      ov.z = o[mt][nt][2]; ov.w = o[mt][nt][3];
      *(float4*)(Op + (nt * 16 + lm) * 128 + d0) = ov;
    }
  }
}

// ---------------------------------------------------------------------------
// Kernel 4: combine the 2 key-half partials + residual + BN (verified in R5).
// ---------------------------------------------------------------------------
__global__ __launch_bounds__(256) void combine(
    const float* __restrict__ Ow, const float* __restrict__ lw,
    const float* __restrict__ x,
    const float* __restrict__ gamma, const float* __restrict__ beta,
    const float* __restrict__ mmean, const float* __restrict__ mvar,
    float* __restrict__ out) {
  int flat4 = blockIdx.x * 256 + threadIdx.x;
  int g  = flat4 * 4;
  int row = g >> 7;
  int c0  = g & 127;
  int bq = row >> 12;
  int n  = row & 4095;
  int qt = n >> 6, qq = n & 63;
  int slot = (bq * 64 + qt) * 2;

  float l = lw[(size_t)slot * 64 + qq] + lw[(size_t)(slot + 1) * 64 + qq];
  float rl = 1.0f / l;
  float4 O0 = *(const float4*)(Ow + (size_t)slot * 8192 + qq * 128 + c0);
  float4 O1 = *(const float4*)(Ow + (size_t)(slot + 1) * 8192 + qq * 128 + c0);
  float4 gm = *(const float4*)(gamma + c0);
  float4 bt = *(const float4*)(beta + c0);
  float4 mm = *(const float4*)(mmean + c0);
  float4 mv = *(const float4*)(mvar + c0);
  float iv0 = gm.x * rsqrtf(mv.x + 1e-3f), iv1 = gm.y * rsqrtf(mv.y + 1e-3f);
  float iv2 = gm.z * rsqrtf(mv.z + 1e-3f), iv3 = gm.w * rsqrtf(mv.w + 1e-3f);
  float4 xr = *(const float4*)(x + g);
  float4 ov;
  ov.x = ((O0.x + O1.x) * rl + xr.x) * iv0 + (bt.x - mm.x * iv0);
  ov.y = ((O0.y + O1.y) * rl + xr.y) * iv1 + (bt.y - mm.y * iv1);
  ov.z = ((O0.z + O1.z) * rl + xr.z) * iv2 + (bt.z - mm.z * iv2);
  ov.w = ((O0.w + O1.w) * rl + xr.w) * iv3 + (bt.w - mm.w * iv3);
  *(float4*)(out + g) = ov;
}

// ---------------------------------------------------------------------------
extern "C" void kernel_launch(void* const* d_in, const int* in_sizes, int n_in,
                              void* d_out, int out_size, void* d_ws, size_t ws_size,
                              hipStream_t stream) {
  const float* x     = (const float*)d_in[0];
  const float* wq    = (const float*)d_in[1];
  const float* bq    = (const float*)d_in[2];
  const float* wk    = (const float*)d_in[3];
  const float* bk    = (const float*)d_in[4];
  const float* wv    = (const float*)d_in[5];
  const float* bv    = (const float*)d_in[6];
  const float* gamma = (const float*)d_in[7];
  const float* beta  = (const float*)d_in[8];
  const float* mmean = (const float*)d_in[9];
  const float* mvar  = (const float*)d_in[10];
  float* out = (float*)d_out;

  unsigned short* wt  = (unsigned short*)d_ws;
  unsigned short* Qg  = wt + 3 * 128 * 128;
  unsigned short* Kg  = Qg + 8 * 4096 * 128;     // pre-swizzled rows
  unsigned short* Vtg = Kg + 8 * 4096 * 128;
  float* Ow = (float*)(Vtg + 8 * 4096 * 128);    // 1024 slots x 64 x 128 fp32
  float* lw = Ow + (size_t)1024 * 8192;          // 1024 slots x 64 fp32

  prep_wt<<<dim3(3, 16), dim3(256), 0, stream>>>(wq, wk, wv, wt);
  qkv_proj<<<dim3(512, 3), dim3(256), 0, stream>>>(x, wt, bq, bk, bv, Qg, Kg, Vtg);
  flash_attn<<<dim3(1024), dim3(256), 0, stream>>>(Qg, Kg, Vtg, Ow, lw);
  combine<<<dim3(4096), dim3(256), 0, stream>>>(Ow, lw, x, gamma, beta, mmean, mvar, out);
}

// Round 10
// 214.867 us; speedup vs baseline: 1.0485x; 1.0485x over previous
//
#include <hip/hip_runtime.h>

// Self-attention (B=8, N=4096, C=128) + residual + inference BatchNorm.
// R10: R8's proven DMA-dbuf flash (best: 116us) + ONE targeted fix: softmax
// exp via __builtin_amdgcn_exp2f (raw v_exp_f32). Plain exp2f lowers to a
// ~20-instr guarded OCML sequence -> the mystery 45% VALUBusy and the serial
// S->P critical path (R8/R9 identical counters despite different structure).
// Also: P pack by truncation (validated R9). Split-K/combine dropped.
//
// ws: Wt 96KB | Qg 8M | Kg(swizzled) 8M | Vtg 8M  (~25.3 MB)

typedef __attribute__((ext_vector_type(8))) short bf16x8;
typedef __attribute__((ext_vector_type(4))) float f32x4;

__device__ __forceinline__ unsigned short f2bf(float f) {
  unsigned int u = __builtin_bit_cast(unsigned int, f);
  u += 0x7fffu + ((u >> 16) & 1u);   // RNE
  return (unsigned short)(u >> 16);
}
__device__ __forceinline__ unsigned int pack2(float a, float b) {
  return (unsigned int)f2bf(a) | ((unsigned int)f2bf(b) << 16);
}
// truncating pack (P in [0,1]: bias negligible vs threshold; 3 VALU vs ~12)
__device__ __forceinline__ unsigned int pack2t(float a, float b) {
  return (__builtin_bit_cast(unsigned int, a) >> 16) |
         (__builtin_bit_cast(unsigned int, b) & 0xFFFF0000u);
}
// raw v_exp_f32 (args bounded: |s~| <~ 15, no guards needed)
__device__ __forceinline__ float fexp2(float x) {
  return __builtin_amdgcn_exp2f(x);
}

// async global->LDS DMA, 16B/lane: lds dest = uniform base + lane*16
__device__ __forceinline__ void dma16(const void* g, void* l) {
  __builtin_amdgcn_global_load_lds(
      (const __attribute__((address_space(1))) unsigned int*)g,
      (__attribute__((address_space(3))) unsigned int*)l, 16, 0, 0);
}

// 1/sqrt(128) * log2(e): softmax in exp2 domain; folded into Wq/bq.
#define SCALE_Q (0.08838834764831845f * 1.44269504088896340f)

// ---------------------------------------------------------------------------
// Kernel 1: W[k][n] fp32 -> Wt[n][k] bf16 (Wq pre-scaled)
// ---------------------------------------------------------------------------
__global__ void prep_wt(const float* __restrict__ wq, const float* __restrict__ wk,
                        const float* __restrict__ wv, unsigned short* __restrict__ wt) {
  const float* W = (blockIdx.x == 0) ? wq : (blockIdx.x == 1 ? wk : wv);
  const float sc = (blockIdx.x == 0) ? SCALE_Q : 1.0f;
  unsigned short* out = wt + blockIdx.x * 16384;
  int id = blockIdx.y * 256 + threadIdx.x;
  int n  = id >> 5;
  int kb = (id & 31) * 4;
#pragma unroll
  for (int k = 0; k < 4; ++k)
    out[n * 128 + kb + k] = f2bf(W[(kb + k) * 128 + n] * sc);
}

// ---------------------------------------------------------------------------
// Kernel 2: QKV projection, grid(512, 3). K stored pre-swizzled (chunk ^ row)
// so flash's linear DMA lands conflict-free in LDS.
// ---------------------------------------------------------------------------
__global__ __launch_bounds__(256) void qkv_proj(
    const float* __restrict__ x, const unsigned short* __restrict__ wt,
    const float* __restrict__ bq, const float* __restrict__ bk, const float* __restrict__ bv,
    unsigned short* __restrict__ Qg, unsigned short* __restrict__ Kg,
    unsigned short* __restrict__ Vtg) {
  __shared__ unsigned short xs[64 * 128];    // swizzled bf16 x tile (16 KB)
  __shared__ unsigned short obuf[9216];      // bounce buffer (18 KB)
  const int t = threadIdx.x;
  const int p = blockIdx.y;
  const int rowblk = blockIdx.x * 64;

#pragma unroll
  for (int i = 0; i < 8; ++i) {
    int flat = t * 4 + i * 1024;
    int row = flat >> 7, col = flat & 127;
    float4 v = *(const float4*)(x + (size_t)(rowblk + row) * 128 + col);
    unsigned int u0 = pack2(v.x, v.y), u1 = pack2(v.z, v.w);
    int pos = (col >> 3) ^ (row & 15);
    *(uint2*)(xs + row * 128 + pos * 8 + (col & 7)) = make_uint2(u0, u1);
  }
  __syncthreads();

  const int lane = t & 63, wv_ = t >> 6;
  const int lm = lane & 15, quad = lane >> 4;

  bf16x8 a[4];
  {
    int row = wv_ * 16 + lm;
#pragma unroll
    for (int ks = 0; ks < 4; ++ks)
      a[ks] = __builtin_bit_cast(bf16x8,
          *(const uint4*)(xs + row * 128 + (((ks * 4 + quad) ^ lm) * 8)));
  }

  const unsigned short* w = wt + p * 16384;
  const float* bias = (p == 0) ? bq : (p == 1 ? bk : bv);
  const float bsc = (p == 0) ? SCALE_Q : 1.0f;

  const f32x4 zero4 = {0.f, 0.f, 0.f, 0.f};
  f32x4 acc[8];
#pragma unroll
  for (int ct = 0; ct < 8; ++ct) acc[ct] = zero4;

#pragma unroll
  for (int ct = 0; ct < 8; ++ct) {
    int n = ct * 16 + lm;
    const uint4* wp = (const uint4*)(w + n * 128 + quad * 8);
#pragma unroll
    for (int ks = 0; ks < 4; ++ks) {
      bf16x8 bfr = __builtin_bit_cast(bf16x8, wp[ks * 4]);
      acc[ct] = __builtin_amdgcn_mfma_f32_16x16x32_bf16(a[ks], bfr, acc[ct], 0, 0, 0);
    }
  }

  const int b   = rowblk >> 12;
  const int nb0 = rowblk & 4095;

  if (p < 2) {
    int rowb = wv_ * 16 + quad * 4;
#pragma unroll
    for (int ct = 0; ct < 8; ++ct) {
      int c = ct * 16 + lm;
      float bb = bias[c] * bsc;
#pragma unroll
      for (int r = 0; r < 4; ++r)
        obuf[(rowb + r) * 136 + c] = f2bf(acc[ct][r] + bb);
    }
    __syncthreads();
    unsigned short* og = (p == 0) ? Qg : Kg;
    int row = t >> 2;
#pragma unroll
    for (int j = 0; j < 4; ++j) {
      int ch = (t & 3) * 4 + j;
      int pos = (p == 1) ? (ch ^ (row & 15)) : ch;   // K: pre-swizzle for DMA
      uint4 vv = *(const uint4*)(obuf + row * 136 + ch * 8);
      *(uint4*)(og + (size_t)(rowblk + row) * 128 + pos * 8) = vv;
    }
  } else {
    int key_base = wv_ * 16 + quad * 4;
#pragma unroll
    for (int ct = 0; ct < 8; ++ct) {
      int c = ct * 16 + lm;
      float bb = bias[c];
      unsigned int u0 = pack2(acc[ct][0] + bb, acc[ct][1] + bb);
      unsigned int u1 = pack2(acc[ct][2] + bb, acc[ct][3] + bb);
      *(uint2*)(obuf + c * 72 + key_base) = make_uint2(u0, u1);
    }
    __syncthreads();
    int d = t >> 1;
#pragma unroll
    for (int j = 0; j < 4; ++j) {
      int ch = (t & 1) * 4 + j;
      uint4 vv = *(const uint4*)(obuf + d * 72 + ch * 8);
      *(uint4*)(Vtg + (size_t)b * 524288 + (size_t)d * 4096 + nb0 + ch * 8) = vv;
    }
  }
}

// ---------------------------------------------------------------------------
// Kernel 3: flash attention, async-K m97-style (R8 core).
// grid(512) = 8b (XCD-local K/V) x 64 q-tiles of 64 rows; 256 thr = 4 waves.
// Per 128-key tile: S from LDS-K (DMA'd) + reg-Q, v_exp_f32 softmax -> P LDS,
// barrier1, DMA K[t+1], PV from LDS-P + reg-V, barrier2 (drains DMA).
// ---------------------------------------------------------------------------
__global__ __launch_bounds__(256, 2) void flash_attn(
    const unsigned short* __restrict__ Qg, const unsigned short* __restrict__ Kg,
    const unsigned short* __restrict__ Vtg, const float* __restrict__ x,
    const float* __restrict__ gamma, const float* __restrict__ beta,
    const float* __restrict__ mmean, const float* __restrict__ mvar,
    float* __restrict__ out) {
  __shared__ unsigned short Kt[2][16384];   // 2 x 32 KB, swizzled rows
  __shared__ unsigned short Pbuf[8192];     // 16 KB (64 q x 128 key); lred after loop

  const int b  = blockIdx.x & 7;
  const int qt = blockIdx.x >> 3;          // 0..63
  const int t = threadIdx.x;
  const int lane = t & 63;
  const int w = t >> 6;                    // 0..3
  const int lm = lane & 15, quad = lane >> 4;
  const int q0 = qt * 64;

  const unsigned short* Qb = Qg  + (size_t)b * 524288;
  const unsigned short* Kb = Kg  + (size_t)b * 524288;
  const unsigned short* Vb = Vtg + (size_t)b * 524288;

  // Q as B-fragments (k=d, n=q), register-resident (pre-scaled)
  bf16x8 qf[4][4];
#pragma unroll
  for (int nt = 0; nt < 4; ++nt) {
    const uint4* qp = (const uint4*)(Qb + (size_t)(q0 + nt * 16 + lm) * 128 + quad * 8);
#pragma unroll
    for (int ks = 0; ks < 4; ++ks) qf[nt][ks] = __builtin_bit_cast(bf16x8, qp[ks * 4]);
  }

  const f32x4 zero4 = {0.f, 0.f, 0.f, 0.f};
  f32x4 o[2][4];
#pragma unroll
  for (int mt = 0; mt < 2; ++mt)
#pragma unroll
    for (int nt = 0; nt < 4; ++nt) o[mt][nt] = zero4;
  float lp[4] = {0.f, 0.f, 0.f, 0.f};

  // preload K tile 0 (each wave DMAs its 8 KB quarter)
  {
    const unsigned short* src = Kb + (size_t)w * 4096 + lane * 8;
    unsigned short* dst = &Kt[0][w * 4096];
#pragma unroll
    for (int j = 0; j < 8; ++j) dma16(src + j * 512, dst + j * 512);
  }
  __syncthreads();   // drains DMA: K[0] resident

#pragma unroll 1
  for (int kt = 0; kt < 32; ++kt) {
    const int bi = kt & 1;
    const int key0 = kt * 128;

    // V^T rows (wave's 32 d) register-direct; drained at barrier 1
    bf16x8 vf[2][4];
#pragma unroll
    for (int mt = 0; mt < 2; ++mt) {
      const uint4* vp = (const uint4*)(Vb + (size_t)(w * 32 + mt * 16 + lm) * 4096 + key0 + quad * 8);
#pragma unroll
      for (int ks = 0; ks < 4; ++ks) vf[mt][ks] = __builtin_bit_cast(bf16x8, vp[ks * 4]);
    }

    // S^T = K * Q^T from LDS K (swizzled chunks)
    f32x4 sa[2][4];
#pragma unroll
    for (int mt = 0; mt < 2; ++mt)
#pragma unroll
      for (int nt = 0; nt < 4; ++nt) sa[mt][nt] = zero4;
#pragma unroll
    for (int mt = 0; mt < 2; ++mt) {
      const unsigned short* kr = &Kt[bi][(w * 32 + mt * 16 + lm) * 128];
      bf16x8 kf[4];
#pragma unroll
      for (int ks = 0; ks < 4; ++ks)
        kf[ks] = __builtin_bit_cast(bf16x8, *(const uint4*)(kr + ((ks * 4 + quad) ^ lm) * 8));
#pragma unroll
      for (int ks = 0; ks < 4; ++ks)
#pragma unroll
        for (int nt = 0; nt < 4; ++nt)
          sa[mt][nt] = __builtin_amdgcn_mfma_f32_16x16x32_bf16(kf[ks], qf[nt][ks], sa[mt][nt], 0, 0, 0);
    }

    // no-max softmax: P = exp2(S~) via raw v_exp_f32; truncating bf16 pack
    {
      unsigned short* Ps = Pbuf;
      const int sub = (quad & 1) * 4;
#pragma unroll
      for (int mt = 0; mt < 2; ++mt) {
        int c16 = w * 4 + mt * 2 + (quad >> 1);
        int pos = c16 ^ lm;
#pragma unroll
        for (int nt = 0; nt < 4; ++nt) {
          float e0 = fexp2(sa[mt][nt][0]), e1 = fexp2(sa[mt][nt][1]);
          float e2 = fexp2(sa[mt][nt][2]), e3 = fexp2(sa[mt][nt][3]);
          lp[nt] += (e0 + e1) + (e2 + e3);
          *(uint2*)(Ps + (nt * 16 + lm) * 128 + pos * 8 + sub) =
              make_uint2(pack2t(e0, e1), pack2t(e2, e3));
        }
      }
    }
    __syncthreads();   // barrier 1: P complete, K[t] free, vf drained

    // issue async DMA for K[t+1] into the other buffer (drains at barrier 2)
    if (kt + 1 < 32) {
      const unsigned short* src = Kb + (size_t)(kt + 1) * 16384 + w * 4096 + lane * 8;
      unsigned short* dst = &Kt[bi ^ 1][w * 4096];
#pragma unroll
      for (int j = 0; j < 8; ++j) dma16(src + j * 512, dst + j * 512);
    }

    // O^T += V^T * P^T (P from LDS, V in regs)
    {
      const uint4* Pr = (const uint4*)Pbuf;
#pragma unroll
      for (int nt = 0; nt < 4; ++nt) {
        bf16x8 pf[4];
#pragma unroll
        for (int ks = 0; ks < 4; ++ks)
          pf[ks] = __builtin_bit_cast(bf16x8, Pr[(nt * 16 + lm) * 16 + ((ks * 4 + quad) ^ lm)]);
#pragma unroll
        for (int ks = 0; ks < 4; ++ks)
#pragma unroll
          for (int mt = 0; mt < 2; ++mt)
            o[mt][nt] = __builtin_amdgcn_mfma_f32_16x16x32_bf16(vf[mt][ks], pf[ks], o[mt][nt], 0, 0, 0);
      }
    }
    __syncthreads();   // barrier 2: P free for next tile; K[t+1] DMA drained
  }

  // l reduction: quads (keys) in-wave, then across waves via Pbuf (now free)
  float* lred = (float*)Pbuf;
#pragma unroll
  for (int nt = 0; nt < 4; ++nt) {
    lp[nt] += __shfl_xor(lp[nt], 16);
    lp[nt] += __shfl_xor(lp[nt], 32);
  }
  if (quad == 0) {
#pragma unroll
    for (int nt = 0; nt < 4; ++nt) lred[w * 64 + nt * 16 + lm] = lp[nt];
  }
  __syncthreads();
  float rl[4];
#pragma unroll
  for (int nt = 0; nt < 4; ++nt) {
    int q = nt * 16 + lm;
    rl[nt] = 1.0f / ((lred[q] + lred[64 + q]) + (lred[128 + q] + lred[192 + q]));
  }

  // epilogue: lane holds 4 consecutive d at fixed q -> float4 stores
#pragma unroll
  for (int mt = 0; mt < 2; ++mt) {
    int c0 = w * 32 + mt * 16 + quad * 4;
    float4 gm = *(const float4*)(gamma + c0);
    float4 bt = *(const float4*)(beta + c0);
    float4 mm = *(const float4*)(mmean + c0);
    float4 mv = *(const float4*)(mvar + c0);
    float iv0 = gm.x * rsqrtf(mv.x + 1e-3f), iv1 = gm.y * rsqrtf(mv.y + 1e-3f);
    float iv2 = gm.z * rsqrtf(mv.z + 1e-3f), iv3 = gm.w * rsqrtf(mv.w + 1e-3f);
    float ad0 = bt.x - mm.x * iv0, ad1 = bt.y - mm.y * iv1;
    float ad2 = bt.z - mm.z * iv2, ad3 = bt.w - mm.w * iv3;
#pragma unroll
    for (int nt = 0; nt < 4; ++nt) {
      size_t g = ((size_t)b * 4096 + q0 + nt * 16 + lm) * 128 + c0;
      float4 xr = *(const float4*)(x + g);
      float4 ov;
      ov.x = (o[mt][nt][0] * rl[nt] + xr.x) * iv0 + ad0;
      ov.y = (o[mt][nt][1] * rl[nt] + xr.y) * iv1 + ad1;
      ov.z = (o[mt][nt][2] * rl[nt] + xr.z) * iv2 + ad2;
      ov.w = (o[mt][nt][3] * rl[nt] + xr.w) * iv3 + ad3;
      *(float4*)(out + g) = ov;
    }
  }
}

// ---------------------------------------------------------------------------
extern "C" void kernel_launch(void* const* d_in, const int* in_sizes, int n_in,
                              void* d_out, int out_size, void* d_ws, size_t ws_size,
                              hipStream_t stream) {
  const float* x     = (const float*)d_in[0];
  const float* wq    = (const float*)d_in[1];
  const float* bq    = (const float*)d_in[2];
  const float* wk    = (const float*)d_in[3];
  const float* bk    = (const float*)d_in[4];
  const float* wv    = (const float*)d_in[5];
  const float* bv    = (const float*)d_in[6];
  const float* gamma = (const float*)d_in[7];
  const float* beta  = (const float*)d_in[8];
  const float* mmean = (const float*)d_in[9];
  const float* mvar  = (const float*)d_in[10];
  float* out = (float*)d_out;

  unsigned short* wt  = (unsigned short*)d_ws;
  unsigned short* Qg  = wt + 3 * 128 * 128;
  unsigned short* Kg  = Qg + 8 * 4096 * 128;     // pre-swizzled rows
  unsigned short* Vtg = Kg + 8 * 4096 * 128;

  prep_wt<<<dim3(3, 16), dim3(256), 0, stream>>>(wq, wk, wv, wt);
  qkv_proj<<<dim3(512, 3), dim3(256), 0, stream>>>(x, wt, bq, bk, bv, Qg, Kg, Vtg);
  flash_attn<<<dim3(512), dim3(256), 0, stream>>>(Qg, Kg, Vtg, x, gamma, beta,
                                                  mmean, mvar, out);
}